// Round 1
// baseline (1023.957 us; speedup 1.0000x reference)
//
#include <hip/hip_runtime.h>

// Layout convention for all intermediate activations: (vertex, batch=16, channel),
// channel fastest. Row for vertex j = 16*C contiguous floats -> spiral/pool gathers
// are coalesced and shared across the batch dim.
//
// Workspace: bufA = d_ws + 0        (cap 51,380,224 B  = max a_i)
//            bufB = d_ws + 51380224 (cap 102,760,448 B = max pooled p)
// total required ws = 154,140,672 B.

__device__ __forceinline__ float4 ld4(const float* p) { return *(const float4*)p; }

// ---------------- fused grid-sample + upsample GEMM ----------------
// out x0: (784, 16, 256).  grid (14, 16), 256 threads (thread = channel).
__global__ __launch_bounds__(256) void k_sample_up(
    const float* __restrict__ uv, const float* __restrict__ feat,
    const float* __restrict__ up, float* __restrict__ x0)
{
  __shared__ float feat_l[256][17];   // padded 4x4 image per channel
  const int tid = threadIdx.x;
  const int b   = blockIdx.y;
  const int v0  = blockIdx.x * 56;

  const float* fr = feat + ((size_t)b*256 + tid)*16;
  #pragma unroll
  for (int i = 0; i < 16; i += 4) {
    float4 f = ld4(fr + i);
    feat_l[tid][i+0] = f.x; feat_l[tid][i+1] = f.y;
    feat_l[tid][i+2] = f.z; feat_l[tid][i+3] = f.w;
  }
  // each thread only reads its own feat_l row -> no barrier needed

  float xg[64];
  #pragma unroll
  for (int p = 0; p < 64; ++p) {
    float gx = uv[((size_t)b*64 + p)*2 + 0];
    float gy = uv[((size_t)b*64 + p)*2 + 1];
    gx = fminf(fmaxf((gx - 0.5f)*2.f, -1.f), 1.f);
    gy = fminf(fmaxf((gy - 0.5f)*2.f, -1.f), 1.f);
    float x = (gx + 1.f)*0.5f*3.f;       // align_corners, w-1 = 3
    float y = (gy + 1.f)*0.5f*3.f;
    float fx = floorf(x), fy = floorf(y);
    int ix0 = (int)fx, iy0 = (int)fy;
    float wx = x - fx, wy = y - fy;
    int ix1 = ix0 + 1 > 3 ? 3 : ix0 + 1; // pad reads carry zero weight -> clamp ok
    int iy1 = iy0 + 1 > 3 ? 3 : iy0 + 1;
    float v00 = feat_l[tid][iy0*4+ix0];
    float v01 = feat_l[tid][iy0*4+ix1];
    float v10 = feat_l[tid][iy1*4+ix0];
    float v11 = feat_l[tid][iy1*4+ix1];
    xg[p] = (1.f-wy)*((1.f-wx)*v00 + wx*v01) + wy*((1.f-wx)*v10 + wx*v11);
  }

  // x0[v,b,c] = sum_p up[v,p] * xg[p]   (up reads are wave-uniform -> scalar loads)
  for (int vv = 0; vv < 56; vv += 4) {
    float a0 = 0.f, a1 = 0.f, a2 = 0.f, a3 = 0.f;
    const float* u0 = up + (size_t)(v0+vv  )*64;
    const float* u1 = up + (size_t)(v0+vv+1)*64;
    const float* u2 = up + (size_t)(v0+vv+2)*64;
    const float* u3 = up + (size_t)(v0+vv+3)*64;
    #pragma unroll
    for (int p = 0; p < 64; ++p) {
      float xv = xg[p];
      a0 += u0[p]*xv; a1 += u1[p]*xv; a2 += u2[p]*xv; a3 += u3[p]*xv;
    }
    float* o = x0 + ((size_t)(v0+vv)*16 + b)*256 + tid;
    o[0*16*256] = a0; o[1*16*256] = a1; o[2*16*256] = a2; o[3*16*256] = a3;
  }
}

// ---------------- mesh up-pool ----------------
// out[v,:,:] = sum_k val[3v+k] * x[col[3v+k],:,:].  grid = n_out blocks.
__global__ __launch_bounds__(256) void k_pool(
    const float* __restrict__ x, const int* __restrict__ col,
    const float* __restrict__ val, float* __restrict__ out, int C16)
{
  const int v = blockIdx.x;
  const int c0 = col[3*v+0], c1 = col[3*v+1], c2 = col[3*v+2];
  const float w0 = val[3*v+0], w1 = val[3*v+1], w2 = val[3*v+2];
  const float4* r0 = (const float4*)(x + (size_t)c0*C16);
  const float4* r1 = (const float4*)(x + (size_t)c1*C16);
  const float4* r2 = (const float4*)(x + (size_t)c2*C16);
  float4* o = (float4*)(out + (size_t)v*C16);
  const int n4 = C16 >> 2;
  for (int i = threadIdx.x; i < n4; i += 256) {
    float4 A = r0[i], B = r1[i], Cv = r2[i], R;
    R.x = w0*A.x + w1*B.x + w2*Cv.x;
    R.y = w0*A.y + w1*B.y + w2*Cv.y;
    R.z = w0*A.z + w1*B.z + w2*Cv.z;
    R.w = w0*A.w + w1*B.w + w2*Cv.w;
    o[i] = R;
  }
}

// ---------------- fused spiral-gather + depthwise conv + pointwise GEMM ----------------
// out[(v,b), co] = relu( sum_ci pw[ci,co] * sum_s dw[ci,s]*pin[(idx[v,s],b), ci] )
// block: 4 vertices x 16 batches = 64 M-rows, full CO.  grid = n_out/4.
template<int CI, int CO, bool RELU>
__global__ __launch_bounds__(256, (CO==64)?4:3) void k_conv(
    const float* __restrict__ pin, const int* __restrict__ idx,
    const float* __restrict__ dw, const float* __restrict__ pw,
    float* __restrict__ out)
{
  constexpr int KC  = (CO == 256) ? 32 : 64;   // K-chunk
  constexpr int TM  = (CO == 256) ? 8 : 4;     // rows / thread
  constexpr int TN  = (CO == 64) ? 4 : 8;      // cols / thread (split into 2 float4s)
  constexpr int CGN = CO / TN;                 // col groups
  constexpr int MI  = KC / 4;                  // build rows per thread

  __shared__ float a_l[KC][68];   // A^T chunk [k][m], +4 pad
  __shared__ float b_l[KC][CO];   // pw chunk  [k][n]
  __shared__ int   idx_l[36];

  const int tid = threadIdx.x;
  const int v0  = blockIdx.x * 4;

  if (tid < 36) idx_l[tid] = idx[v0*9 + tid];

  const int kl = tid & (KC - 1);
  const int bg = tid / KC;
  const int cg = tid % CGN;
  const int rg = tid / CGN;

  float acc[TM][TN];
  #pragma unroll
  for (int i = 0; i < TM; ++i)
    #pragma unroll
    for (int j = 0; j < TN; ++j) acc[i][j] = 0.f;

  for (int kc = 0; kc < CI; kc += KC) {
    __syncthreads();
    // stage pw chunk (coalesced, contiguous)
    const float* pwsrc = pw + (size_t)kc*CO;
    float* bl = &b_l[0][0];
    #pragma unroll
    for (int i = 0; i < KC*CO/256; ++i) bl[tid + i*256] = pwsrc[tid + i*256];
    // this thread's depthwise weights for channel kc+kl
    float dws[9];
    #pragma unroll
    for (int s = 0; s < 9; ++s) dws[s] = dw[(size_t)(kc+kl)*9 + s];
    // build A^T: 9 coalesced gathered rows per (vertex, batch)
    #pragma unroll
    for (int i = 0; i < MI; ++i) {
      int m = bg*MI + i;
      int vloc = m >> 4, bb = m & 15;
      const float* prow = pin + kc + kl + (size_t)bb*CI;
      float y = 0.f;
      #pragma unroll
      for (int s = 0; s < 9; ++s) {
        int r = idx_l[vloc*9 + s];
        y += dws[s] * prow[(size_t)r*16*CI];
      }
      a_l[kl][m] = y;
    }
    __syncthreads();
    // register-tiled GEMM on the chunk
    #pragma unroll 8
    for (int k = 0; k < KC; ++k) {
      float av[TM], bv[TN];
      *(float4*)&av[0] = ld4(&a_l[k][TM*rg]);
      if constexpr (TM == 8) *(float4*)&av[4] = ld4(&a_l[k][TM*rg + 4]);
      *(float4*)&bv[0] = ld4(&b_l[k][4*cg]);
      if constexpr (TN == 8) *(float4*)&bv[4] = ld4(&b_l[k][CO/2 + 4*cg]);
      #pragma unroll
      for (int i = 0; i < TM; ++i)
        #pragma unroll
        for (int j = 0; j < TN; ++j)
          acc[i][j] += av[i]*bv[j];
    }
  }
  // epilogue
  #pragma unroll
  for (int i = 0; i < TM; ++i) {
    size_t ro = ((size_t)(v0*16 + TM*rg + i))*CO;
    float4 o0;
    o0.x = acc[i][0]; o0.y = acc[i][1]; o0.z = acc[i][2]; o0.w = acc[i][3];
    if constexpr (RELU) {
      o0.x = fmaxf(o0.x, 0.f); o0.y = fmaxf(o0.y, 0.f);
      o0.z = fmaxf(o0.z, 0.f); o0.w = fmaxf(o0.w, 0.f);
    }
    *(float4*)(out + ro + 4*cg) = o0;
    if constexpr (TN == 8) {
      float4 o1;
      o1.x = acc[i][4]; o1.y = acc[i][5]; o1.z = acc[i][6]; o1.w = acc[i][7];
      if constexpr (RELU) {
        o1.x = fmaxf(o1.x, 0.f); o1.y = fmaxf(o1.y, 0.f);
        o1.z = fmaxf(o1.z, 0.f); o1.w = fmaxf(o1.w, 0.f);
      }
      *(float4*)(out + ro + CO/2 + 4*cg) = o1;
    }
  }
}

// ---------------- head: spiral conv 64 -> 3, output in (b, v, 3) order ----------------
// one wave per (v,b) row; lane = ci; cross-lane reduce for the 3 outputs.
__global__ __launch_bounds__(256) void k_head(
    const float* __restrict__ a, const int* __restrict__ idx,
    const float* __restrict__ dwh, const float* __restrict__ pwh,
    float* __restrict__ out, int nvert)
{
  const int wid  = blockIdx.x*4 + (threadIdx.x >> 6);
  const int lane = threadIdx.x & 63;
  const int v = wid >> 4, b = wid & 15;
  float y = 0.f;
  #pragma unroll
  for (int s = 0; s < 9; ++s) {
    int r = idx[v*9 + s];                       // wave-uniform -> scalar load
    y += dwh[lane*9 + s] * a[((size_t)r*16 + b)*64 + lane];
  }
  float p0 = y * pwh[lane*3+0];
  float p1 = y * pwh[lane*3+1];
  float p2 = y * pwh[lane*3+2];
  #pragma unroll
  for (int o = 32; o > 0; o >>= 1) {
    p0 += __shfl_xor(p0, o, 64);
    p1 += __shfl_xor(p1, o, 64);
    p2 += __shfl_xor(p2, o, 64);
  }
  if (lane == 0) {
    size_t off = ((size_t)b*nvert + v)*3;
    out[off+0] = p0; out[off+1] = p1; out[off+2] = p2;
  }
}

extern "C" void kernel_launch(void* const* d_in, const int* in_sizes, int n_in,
                              void* d_out, int out_size, void* d_ws, size_t ws_size,
                              hipStream_t stream)
{
  // setup_inputs() dict order
  const float* uv   = (const float*)d_in[0];
  const float* feat = (const float*)d_in[1];
  const float* up   = (const float*)d_in[2];
  const float* dw0  = (const float*)d_in[3];
  const float* pw0  = (const float*)d_in[4];
  const float* dw1  = (const float*)d_in[5];
  const float* pw1  = (const float*)d_in[6];
  const float* dw2  = (const float*)d_in[7];
  const float* pw2  = (const float*)d_in[8];
  const float* dw3  = (const float*)d_in[9];
  const float* pw3  = (const float*)d_in[10];
  const float* dwh  = (const float*)d_in[11];
  const float* pwh  = (const float*)d_in[12];
  const int*   sp0  = (const int*)d_in[13];
  const int*   col0 = (const int*)d_in[14];
  const float* val0 = (const float*)d_in[15];
  const int*   sp1  = (const int*)d_in[16];
  const int*   col1 = (const int*)d_in[17];
  const float* val1 = (const float*)d_in[18];
  const int*   sp2  = (const int*)d_in[19];
  const int*   col2 = (const int*)d_in[20];
  const float* val2 = (const float*)d_in[21];
  const int*   sp3  = (const int*)d_in[22];
  const int*   col3 = (const int*)d_in[23];
  const float* val3 = (const float*)d_in[24];

  float* bufA = (float*)d_ws;                          // cap 51,380,224 B
  float* bufB = (float*)((char*)d_ws + 51380224);      // cap 102,760,448 B
  float* outp = (float*)d_out;

  // x0 (784,16,256) in bufA
  k_sample_up<<<dim3(14,16,1), 256, 0, stream>>>(uv, feat, up, bufA);
  // level 1: 784 -> 1568, 256ch
  k_pool<<<1568, 256, 0, stream>>>(bufA, col3, val3, bufB, 16*256);
  k_conv<256,256,true><<<392, 256, 0, stream>>>(bufB, sp3, dw0, pw0, bufA);
  // level 2: 1568 -> 3136, 256ch
  k_pool<<<3136, 256, 0, stream>>>(bufA, col2, val2, bufB, 16*256);
  k_conv<256,256,true><<<784, 256, 0, stream>>>(bufB, sp2, dw1, pw1, bufA);
  // level 3: 3136 -> 6272, 256 -> 128
  k_pool<<<6272, 256, 0, stream>>>(bufA, col1, val1, bufB, 16*256);
  k_conv<256,128,true><<<1568, 256, 0, stream>>>(bufB, sp1, dw2, pw2, bufA);
  // level 4: 6272 -> 12544, 128 -> 64
  k_pool<<<12544, 256, 0, stream>>>(bufA, col0, val0, bufB, 16*128);
  k_conv<128,64,true><<<3136, 256, 0, stream>>>(bufB, sp0, dw3, pw3, bufA);
  // head -> (b, v, 3)
  k_head<<<50176, 256, 0, stream>>>(bufA, sp0, dwh, pwh, outp, 12544);
}

// Round 3
// 749.245 us; speedup vs baseline: 1.3667x; 1.3667x over previous
//
#include <hip/hip_runtime.h>

// Activations: (vertex, batch=16, channel), channel fastest, all fp32.
// bufA (fp32, cap 51,380,224 B) = conv outputs / x0.
// bufB (fp32, cap 102,760,448 B) = pool outputs (conv inputs).
// Total d_ws use: 154,140,672 B (same as the passing round-1 layout).
//
// Split-precision pointwise weights pwT_hi/lo (fp16, [CO][CI]) live in d_out
// as scratch (688,128 B << d_out's 2.4 MB): k_prep writes them, convs read
// them, k_head fully overwrites d_out afterwards (same-stream ordering).

typedef _Float16 half8 __attribute__((ext_vector_type(8)));
typedef float    f32x4 __attribute__((ext_vector_type(4)));

__device__ __forceinline__ float4 ld4(const float* p) { return *(const float4*)p; }

__device__ __forceinline__ unsigned short hbits(float v) {
  _Float16 h = (_Float16)v; unsigned short u; __builtin_memcpy(&u, &h, 2); return u;
}

// split v = hi + lo*2^-11, lo pre-scaled by 2048 (stays fp16-normal)
__device__ __forceinline__ void split2h(float v, unsigned short& h, unsigned short& l) {
  _Float16 hf = (_Float16)v;
  float hif; { hif = (float)hf; }
  _Float16 lf = (_Float16)((v - hif) * 2048.0f);
  __builtin_memcpy(&h, &hf, 2); __builtin_memcpy(&l, &lf, 2);
}

// ---------------- prep: transpose+split pw -> pwT_hi / pwT_lo fp16 [CO][CI] ----------------
// hi arrays at dst[0..172031], lo arrays at dst[172032..344063].
__global__ __launch_bounds__(256) void k_prep(
    const float* __restrict__ pw0, const float* __restrict__ pw1,
    const float* __restrict__ pw2, const float* __restrict__ pw3,
    unsigned short* __restrict__ dst)
{
  const int b = blockIdx.x, t = threadIdx.x;
  const float* src; int ci_sh, co, f, off;
  if (b < 256)      { src = pw0; ci_sh = 8; co = 256; f = b*256 + t;       off = 0; }
  else if (b < 512) { src = pw1; ci_sh = 8; co = 256; f = (b-256)*256 + t; off = 65536; }
  else if (b < 640) { src = pw2; ci_sh = 8; co = 128; f = (b-512)*256 + t; off = 131072; }  // pw2 CI=256!
  else              { src = pw3; ci_sh = 7; co = 64;  f = (b-640)*256 + t; off = 163840; }
  const int n = f >> ci_sh, k = f & ((1 << ci_sh) - 1);
  float v = src[(size_t)k*co + n];
  unsigned short h, l; split2h(v, h, l);
  dst[off + f]          = h;
  dst[172032 + off + f] = l;
}

// ---------------- fused grid-sample + upsample GEMM (fp32) ----------------
__global__ __launch_bounds__(256) void k_sample_up(
    const float* __restrict__ uv, const float* __restrict__ feat,
    const float* __restrict__ up, float* __restrict__ x0)
{
  __shared__ float feat_l[256][17];
  const int tid = threadIdx.x;
  const int b   = blockIdx.y;
  const int v0  = blockIdx.x * 56;

  const float* fr = feat + ((size_t)b*256 + tid)*16;
  #pragma unroll
  for (int i = 0; i < 16; i += 4) {
    float4 f = ld4(fr + i);
    feat_l[tid][i+0] = f.x; feat_l[tid][i+1] = f.y;
    feat_l[tid][i+2] = f.z; feat_l[tid][i+3] = f.w;
  }
  float xg[64];
  #pragma unroll
  for (int p = 0; p < 64; ++p) {
    float gx = uv[((size_t)b*64 + p)*2 + 0];
    float gy = uv[((size_t)b*64 + p)*2 + 1];
    gx = fminf(fmaxf((gx - 0.5f)*2.f, -1.f), 1.f);
    gy = fminf(fmaxf((gy - 0.5f)*2.f, -1.f), 1.f);
    float x = (gx + 1.f)*0.5f*3.f;
    float y = (gy + 1.f)*0.5f*3.f;
    float fx = floorf(x), fy = floorf(y);
    int ix0 = (int)fx, iy0 = (int)fy;
    float wx = x - fx, wy = y - fy;
    int ix1 = ix0 + 1 > 3 ? 3 : ix0 + 1;
    int iy1 = iy0 + 1 > 3 ? 3 : iy0 + 1;
    float v00 = feat_l[tid][iy0*4+ix0];
    float v01 = feat_l[tid][iy0*4+ix1];
    float v10 = feat_l[tid][iy1*4+ix0];
    float v11 = feat_l[tid][iy1*4+ix1];
    xg[p] = (1.f-wy)*((1.f-wx)*v00 + wx*v01) + wy*((1.f-wx)*v10 + wx*v11);
  }
  for (int vv = 0; vv < 56; vv += 4) {
    float a0 = 0.f, a1 = 0.f, a2 = 0.f, a3 = 0.f;
    const float* u0 = up + (size_t)(v0+vv  )*64;
    const float* u1 = up + (size_t)(v0+vv+1)*64;
    const float* u2 = up + (size_t)(v0+vv+2)*64;
    const float* u3 = up + (size_t)(v0+vv+3)*64;
    #pragma unroll
    for (int p = 0; p < 64; ++p) {
      float xv = xg[p];
      a0 += u0[p]*xv; a1 += u1[p]*xv; a2 += u2[p]*xv; a3 += u3[p]*xv;
    }
    float* o = x0 + ((size_t)(v0+vv)*16 + b)*256 + tid;
    o[0*16*256] = a0; o[1*16*256] = a1; o[2*16*256] = a2; o[3*16*256] = a3;
  }
}

// ---------------- mesh up-pool: fp32 -> fp32 ----------------
__global__ __launch_bounds__(256) void k_pool(
    const float* __restrict__ x, const int* __restrict__ col,
    const float* __restrict__ val, float* __restrict__ out, int C16)
{
  const int v = blockIdx.x;
  const int c0 = col[3*v+0], c1 = col[3*v+1], c2 = col[3*v+2];
  const float w0 = val[3*v+0], w1 = val[3*v+1], w2 = val[3*v+2];
  const float4* r0 = (const float4*)(x + (size_t)c0*C16);
  const float4* r1 = (const float4*)(x + (size_t)c1*C16);
  const float4* r2 = (const float4*)(x + (size_t)c2*C16);
  float4* o = (float4*)(out + (size_t)v*C16);
  const int n4 = C16 >> 2;
  for (int i = threadIdx.x; i < n4; i += 256) {
    float4 A = r0[i], B = r1[i], Cv = r2[i], R;
    R.x = w0*A.x + w1*B.x + w2*Cv.x;
    R.y = w0*A.y + w1*B.y + w2*Cv.y;
    R.z = w0*A.z + w1*B.z + w2*Cv.z;
    R.w = w0*A.w + w1*B.w + w2*Cv.w;
    o[i] = R;
  }
}

// ---------------- fused spiral-gather + dwconv(fp32) + split-fp16 MFMA pointwise ----------------
// Block = 64 M-rows (4 vertices x 16 batch) x full CO.  A panel (64 x CI) built
// in fp32 then split hi/lo into two LDS panels; D = Ah*Bh + (Ah*Bl + Al*Bh)*2^-11.
template<int CI, int CO, bool RELU>
__global__ __launch_bounds__(256, (CI==128) ? 4 : 2) void k_conv(
    const float* __restrict__ pin, const int* __restrict__ idx,
    const float* __restrict__ dw,
    const unsigned short* __restrict__ bhp, const unsigned short* __restrict__ blp,
    float* __restrict__ out)
{
  constexpr int KG     = CI/4;      // channel groups of 4 (16B fp32 gather)
  constexpr int MPT    = 64/(256/KG);
  constexpr int AROW   = CI + 8;
  constexpr int NTW    = CO/64;
  constexpr int CHUNKS = CI/32;

  __shared__ __align__(16) unsigned short a_hi[64][AROW];
  __shared__ __align__(16) unsigned short a_lo[64][AROW];

  const int t  = threadIdx.x;
  const int v0 = blockIdx.x * 4;

  // ---- build + split A panel ----
  {
    const int kg   = t & (KG - 1);
    const int mb   = (t / KG) * MPT;
    const int vloc = mb >> 4;          // constant per thread (MPT rows stay in one vertex)
    int rows[9];
    #pragma unroll
    for (int s = 0; s < 9; ++s) rows[s] = idx[(v0 + vloc)*9 + s] * (16*CI);
    float dwv[36];
    #pragma unroll
    for (int j = 0; j < 4; ++j)
      #pragma unroll
      for (int s = 0; s < 9; ++s) dwv[j*9 + s] = dw[(size_t)(4*kg + j)*9 + s];

    #pragma unroll 2
    for (int i = 0; i < MPT; ++i) {
      const int m = mb + i;
      const float* base = pin + (size_t)(m & 15)*CI + 4*kg;
      float y0 = 0.f, y1 = 0.f, y2 = 0.f, y3 = 0.f;
      #pragma unroll
      for (int s = 0; s < 9; ++s) {
        float4 g = ld4(base + rows[s]);
        y0 += dwv[s]*g.x; y1 += dwv[9+s]*g.y; y2 += dwv[18+s]*g.z; y3 += dwv[27+s]*g.w;
      }
      unsigned short h0,l0,h1,l1,h2,l2,h3,l3;
      split2h(y0,h0,l0); split2h(y1,h1,l1); split2h(y2,h2,l2); split2h(y3,h3,l3);
      uint2 uh, ul;
      uh.x = (unsigned)h0 | ((unsigned)h1 << 16); uh.y = (unsigned)h2 | ((unsigned)h3 << 16);
      ul.x = (unsigned)l0 | ((unsigned)l1 << 16); ul.y = (unsigned)l2 | ((unsigned)l3 << 16);
      *(uint2*)&a_hi[m][4*kg] = uh;
      *(uint2*)&a_lo[m][4*kg] = ul;
    }
  }
  __syncthreads();

  // ---- split MFMA phase ----
  const int w = t >> 6, l = t & 15, q = (t >> 4) & 3;
  f32x4 ah[4][NTW], ax[4][NTW];
  #pragma unroll
  for (int mt = 0; mt < 4; ++mt)
    #pragma unroll
    for (int n = 0; n < NTW; ++n)
      #pragma unroll
      for (int r = 0; r < 4; ++r) { ah[mt][n][r] = 0.f; ax[mt][n][r] = 0.f; }

  #pragma unroll
  for (int c = 0; c < CHUNKS; ++c) {
    const int k0 = c*32 + q*8;
    half8 fah[4], fal[4], fbh[NTW], fbl[NTW];
    #pragma unroll
    for (int mt = 0; mt < 4; ++mt) {
      fah[mt] = *(const half8*)&a_hi[mt*16 + l][k0];
      fal[mt] = *(const half8*)&a_lo[mt*16 + l][k0];
    }
    #pragma unroll
    for (int n = 0; n < NTW; ++n) {
      const size_t boff = (size_t)((w*NTW + n)*16 + l)*CI + k0;
      fbh[n] = *(const half8*)(bhp + boff);
      fbl[n] = *(const half8*)(blp + boff);
    }
    #pragma unroll
    for (int mt = 0; mt < 4; ++mt)
      #pragma unroll
      for (int n = 0; n < NTW; ++n) {
        ah[mt][n] = __builtin_amdgcn_mfma_f32_16x16x32_f16(fah[mt], fbh[n], ah[mt][n], 0, 0, 0);
        ax[mt][n] = __builtin_amdgcn_mfma_f32_16x16x32_f16(fah[mt], fbl[n], ax[mt][n], 0, 0, 0);
        ax[mt][n] = __builtin_amdgcn_mfma_f32_16x16x32_f16(fal[mt], fbh[n], ax[mt][n], 0, 0, 0);
      }
  }

  // ---- epilogue: D[row=q*4+r][col=lane&15] ----
  #pragma unroll
  for (int mt = 0; mt < 4; ++mt)
    #pragma unroll
    for (int n = 0; n < NTW; ++n) {
      const int colg = (w*NTW + n)*16 + l;
      #pragma unroll
      for (int r = 0; r < 4; ++r) {
        const int row = mt*16 + q*4 + r;
        float v = ah[mt][n][r] + ax[mt][n][r] * (1.0f/2048.0f);
        if (RELU) v = fmaxf(v, 0.f);
        out[(size_t)(v0*16 + row)*CO + colg] = v;
      }
    }
}

// ---------------- head: spiral conv 64 -> 3 (fp32), output (b, v, 3) ----------------
__global__ __launch_bounds__(256) void k_head(
    const float* __restrict__ a, const int* __restrict__ idx,
    const float* __restrict__ dwh, const float* __restrict__ pwh,
    float* __restrict__ out, int nvert)
{
  const int wid  = blockIdx.x*4 + (threadIdx.x >> 6);
  const int lane = threadIdx.x & 63;
  const int v = wid >> 4, b = wid & 15;
  float y = 0.f;
  #pragma unroll
  for (int s = 0; s < 9; ++s) {
    int r = idx[v*9 + s];
    y += dwh[lane*9 + s] * a[((size_t)r*16 + b)*64 + lane];
  }
  float p0 = y * pwh[lane*3+0];
  float p1 = y * pwh[lane*3+1];
  float p2 = y * pwh[lane*3+2];
  #pragma unroll
  for (int o = 32; o > 0; o >>= 1) {
    p0 += __shfl_xor(p0, o, 64);
    p1 += __shfl_xor(p1, o, 64);
    p2 += __shfl_xor(p2, o, 64);
  }
  if (lane == 0) {
    size_t off = ((size_t)b*nvert + v)*3;
    out[off+0] = p0; out[off+1] = p1; out[off+2] = p2;
  }
}

extern "C" void kernel_launch(void* const* d_in, const int* in_sizes, int n_in,
                              void* d_out, int out_size, void* d_ws, size_t ws_size,
                              hipStream_t stream)
{
  const float* uv   = (const float*)d_in[0];
  const float* feat = (const float*)d_in[1];
  const float* up   = (const float*)d_in[2];
  const float* dw0  = (const float*)d_in[3];
  const float* pw0  = (const float*)d_in[4];
  const float* dw1  = (const float*)d_in[5];
  const float* pw1  = (const float*)d_in[6];
  const float* dw2  = (const float*)d_in[7];
  const float* pw2  = (const float*)d_in[8];
  const float* dw3  = (const float*)d_in[9];
  const float* pw3  = (const float*)d_in[10];
  const float* dwh  = (const float*)d_in[11];
  const float* pwh  = (const float*)d_in[12];
  const int*   sp0  = (const int*)d_in[13];
  const int*   col0 = (const int*)d_in[14];
  const float* val0 = (const float*)d_in[15];
  const int*   sp1  = (const int*)d_in[16];
  const int*   col1 = (const int*)d_in[17];
  const float* val1 = (const float*)d_in[18];
  const int*   sp2  = (const int*)d_in[19];
  const int*   col2 = (const int*)d_in[20];
  const float* val2 = (const float*)d_in[21];
  const int*   sp3  = (const int*)d_in[22];
  const int*   col3 = (const int*)d_in[23];
  const float* val3 = (const float*)d_in[24];

  float* bufA = (float*)d_ws;                        // 51,380,224 B
  float* bufB = (float*)((char*)d_ws + 51380224);    // 102,760,448 B
  float* outp = (float*)d_out;

  // split pw tables in d_out scratch (overwritten by k_head at the end)
  unsigned short* pwT = (unsigned short*)d_out;
  unsigned short* h0 = pwT;            unsigned short* L0 = pwT + 172032;
  unsigned short* h1 = pwT + 65536;    unsigned short* L1 = L0 + 65536;
  unsigned short* h2 = pwT + 131072;   unsigned short* L2 = L0 + 131072;
  unsigned short* h3 = pwT + 163840;   unsigned short* L3 = L0 + 163840;

  k_prep<<<672, 256, 0, stream>>>(pw0, pw1, pw2, pw3, pwT);
  k_sample_up<<<dim3(14,16,1), 256, 0, stream>>>(uv, feat, up, bufA);

  k_pool<<<1568, 256, 0, stream>>>(bufA, col3, val3, bufB, 16*256);
  k_conv<256,256,true><<<392, 256, 0, stream>>>(bufB, sp3, dw0, h0, L0, bufA);

  k_pool<<<3136, 256, 0, stream>>>(bufA, col2, val2, bufB, 16*256);
  k_conv<256,256,true><<<784, 256, 0, stream>>>(bufB, sp2, dw1, h1, L1, bufA);

  k_pool<<<6272, 256, 0, stream>>>(bufA, col1, val1, bufB, 16*256);
  k_conv<256,128,true><<<1568, 256, 0, stream>>>(bufB, sp1, dw2, h2, L2, bufA);

  k_pool<<<12544, 256, 0, stream>>>(bufA, col0, val0, bufB, 16*128);
  k_conv<128,64,true><<<3136, 256, 0, stream>>>(bufB, sp0, dw3, h3, L3, bufA);

  k_head<<<50176, 256, 0, stream>>>(bufA, sp0, dwh, pwh, outp, 12544);
}

// Round 4
// 741.010 us; speedup vs baseline: 1.3818x; 1.0111x over previous
//
#include <hip/hip_runtime.h>

// Activations: (vertex, batch=16, channel), channel fastest, stored FP16.
// bufA (fp16, cap 25,690,112 B) = conv outputs / x0.
// bufB (fp16, cap 51,380,224 B) = pool outputs (conv inputs).
// Total d_ws use: 77 MB (ws proven >= 154 MB in round 1).
//
// GEMM numerics: A panel = dwconv(fp32 accum) rounded to fp16 (matches the
// fp16 storage rounding already accepted); B = split hi/lo fp16 (2^-22 weight
// precision). D = Ah*Bh + Ah*Bl*2^-11.  Split pw tables live in d_out scratch
// (688 KB), overwritten by k_head at the end (same-stream ordering).

typedef _Float16 half8 __attribute__((ext_vector_type(8)));
typedef float    f32x4 __attribute__((ext_vector_type(4)));

__device__ __forceinline__ float4 ld4(const float* p) { return *(const float4*)p; }

__device__ __forceinline__ float lo16f(unsigned u) {
  _Float16 h; unsigned short s = (unsigned short)(u & 0xffffu);
  __builtin_memcpy(&h, &s, 2); return (float)h;
}
__device__ __forceinline__ float hi16f(unsigned u) {
  _Float16 h; unsigned short s = (unsigned short)(u >> 16);
  __builtin_memcpy(&h, &s, 2); return (float)h;
}
__device__ __forceinline__ float h2f(unsigned short s) {
  _Float16 h; __builtin_memcpy(&h, &s, 2); return (float)h;
}
__device__ __forceinline__ unsigned short hbits(float v) {
  _Float16 h = (_Float16)v; unsigned short u; __builtin_memcpy(&u, &h, 2); return u;
}
__device__ __forceinline__ unsigned pk2h(float a, float b) {
  return (unsigned)hbits(a) | ((unsigned)hbits(b) << 16);
}
// split v = hi + lo*2^-11, lo pre-scaled by 2048
__device__ __forceinline__ void split2h(float v, unsigned short& h, unsigned short& l) {
  _Float16 hf = (_Float16)v;
  float hif = (float)hf;
  _Float16 lf = (_Float16)((v - hif) * 2048.0f);
  __builtin_memcpy(&h, &hf, 2); __builtin_memcpy(&l, &lf, 2);
}

// ---------------- prep: transpose+split pw -> pwT_hi / pwT_lo fp16 [CO][CI] ----------------
__global__ __launch_bounds__(256) void k_prep(
    const float* __restrict__ pw0, const float* __restrict__ pw1,
    const float* __restrict__ pw2, const float* __restrict__ pw3,
    unsigned short* __restrict__ dst)
{
  const int b = blockIdx.x, t = threadIdx.x;
  const float* src; int ci_sh, co, f, off;
  if (b < 256)      { src = pw0; ci_sh = 8; co = 256; f = b*256 + t;       off = 0; }
  else if (b < 512) { src = pw1; ci_sh = 8; co = 256; f = (b-256)*256 + t; off = 65536; }
  else if (b < 640) { src = pw2; ci_sh = 8; co = 128; f = (b-512)*256 + t; off = 131072; }
  else              { src = pw3; ci_sh = 7; co = 64;  f = (b-640)*256 + t; off = 163840; }
  const int n = f >> ci_sh, k = f & ((1 << ci_sh) - 1);
  float v = src[(size_t)k*co + n];
  unsigned short h, l; split2h(v, h, l);
  dst[off + f]          = h;
  dst[172032 + off + f] = l;
}

// ---------------- fused grid-sample + upsample GEMM -> fp16 x0 ----------------
__global__ __launch_bounds__(256) void k_sample_up(
    const float* __restrict__ uv, const float* __restrict__ feat,
    const float* __restrict__ up, unsigned short* __restrict__ x0)
{
  __shared__ float feat_l[256][17];
  const int tid = threadIdx.x;
  const int b   = blockIdx.y;
  const int v0  = blockIdx.x * 56;

  const float* fr = feat + ((size_t)b*256 + tid)*16;
  #pragma unroll
  for (int i = 0; i < 16; i += 4) {
    float4 f = ld4(fr + i);
    feat_l[tid][i+0] = f.x; feat_l[tid][i+1] = f.y;
    feat_l[tid][i+2] = f.z; feat_l[tid][i+3] = f.w;
  }
  float xg[64];
  #pragma unroll
  for (int p = 0; p < 64; ++p) {
    float gx = uv[((size_t)b*64 + p)*2 + 0];
    float gy = uv[((size_t)b*64 + p)*2 + 1];
    gx = fminf(fmaxf((gx - 0.5f)*2.f, -1.f), 1.f);
    gy = fminf(fmaxf((gy - 0.5f)*2.f, -1.f), 1.f);
    float x = (gx + 1.f)*0.5f*3.f;
    float y = (gy + 1.f)*0.5f*3.f;
    float fx = floorf(x), fy = floorf(y);
    int ix0 = (int)fx, iy0 = (int)fy;
    float wx = x - fx, wy = y - fy;
    int ix1 = ix0 + 1 > 3 ? 3 : ix0 + 1;
    int iy1 = iy0 + 1 > 3 ? 3 : iy0 + 1;
    float v00 = feat_l[tid][iy0*4+ix0];
    float v01 = feat_l[tid][iy0*4+ix1];
    float v10 = feat_l[tid][iy1*4+ix0];
    float v11 = feat_l[tid][iy1*4+ix1];
    xg[p] = (1.f-wy)*((1.f-wx)*v00 + wx*v01) + wy*((1.f-wx)*v10 + wx*v11);
  }
  for (int vv = 0; vv < 56; vv += 4) {
    float a0 = 0.f, a1 = 0.f, a2 = 0.f, a3 = 0.f;
    const float* u0 = up + (size_t)(v0+vv  )*64;
    const float* u1 = up + (size_t)(v0+vv+1)*64;
    const float* u2 = up + (size_t)(v0+vv+2)*64;
    const float* u3 = up + (size_t)(v0+vv+3)*64;
    #pragma unroll
    for (int p = 0; p < 64; ++p) {
      float xv = xg[p];
      a0 += u0[p]*xv; a1 += u1[p]*xv; a2 += u2[p]*xv; a3 += u3[p]*xv;
    }
    unsigned short* o = x0 + ((size_t)(v0+vv)*16 + b)*256 + tid;
    o[0*16*256] = hbits(a0); o[1*16*256] = hbits(a1);
    o[2*16*256] = hbits(a2); o[3*16*256] = hbits(a3);
  }
}

// ---------------- mesh up-pool: fp16 -> fp16 (fp32 math) ----------------
__global__ __launch_bounds__(256) void k_pool(
    const unsigned short* __restrict__ x, const int* __restrict__ col,
    const float* __restrict__ val, unsigned short* __restrict__ out, int C16)
{
  const int v = blockIdx.x;
  const int c0 = col[3*v+0], c1 = col[3*v+1], c2 = col[3*v+2];
  const float w0 = val[3*v+0], w1 = val[3*v+1], w2 = val[3*v+2];
  const uint4* r0 = (const uint4*)(x + (size_t)c0*C16);
  const uint4* r1 = (const uint4*)(x + (size_t)c1*C16);
  const uint4* r2 = (const uint4*)(x + (size_t)c2*C16);
  uint4* o = (uint4*)(out + (size_t)v*C16);
  const int n8 = C16 >> 3;
  for (int i = threadIdx.x; i < n8; i += 256) {
    uint4 A = r0[i], B = r1[i], Cv = r2[i], R;
    R.x = pk2h(w0*lo16f(A.x)+w1*lo16f(B.x)+w2*lo16f(Cv.x),
               w0*hi16f(A.x)+w1*hi16f(B.x)+w2*hi16f(Cv.x));
    R.y = pk2h(w0*lo16f(A.y)+w1*lo16f(B.y)+w2*lo16f(Cv.y),
               w0*hi16f(A.y)+w1*hi16f(B.y)+w2*hi16f(Cv.y));
    R.z = pk2h(w0*lo16f(A.z)+w1*lo16f(B.z)+w2*lo16f(Cv.z),
               w0*hi16f(A.z)+w1*hi16f(B.z)+w2*hi16f(Cv.z));
    R.w = pk2h(w0*lo16f(A.w)+w1*lo16f(B.w)+w2*lo16f(Cv.w),
               w0*hi16f(A.w)+w1*hi16f(B.w)+w2*hi16f(Cv.w));
    o[i] = R;
  }
}

// ---------------- fused spiral-gather + dwconv(fp32) + MFMA pointwise ----------------
// Block = 64 M-rows (4 vertices x 16 batch) x full CO.  A panel (64 x CI fp16)
// built once in LDS; D = Ah*Bh + Ah*Bl*2^-11.  fp16 input: 8 channels / 16B load.
template<int CI, int CO, bool RELU>
__global__ __launch_bounds__(256, (CI==128) ? 4 : 3) void k_conv(
    const unsigned short* __restrict__ pin, const int* __restrict__ idx,
    const float* __restrict__ dw,
    const unsigned short* __restrict__ bhp, const unsigned short* __restrict__ blp,
    unsigned short* __restrict__ out)
{
  constexpr int KG     = CI/8;      // channel groups of 8 (16B fp16 gather)
  constexpr int MPT    = KG/4;      // rows per thread (64*KG/256)
  constexpr int AROW   = CI + 8;
  constexpr int NTW    = CO/64;
  constexpr int CHUNKS = CI/32;

  __shared__ __align__(16) unsigned short a_l[64][AROW];

  const int t  = threadIdx.x;
  const int v0 = blockIdx.x * 4;

  // ---- build A panel ----
  {
    const int kg   = t & (KG - 1);
    const int mb   = (t / KG) * MPT;
    const int vloc = mb >> 4;          // constant per thread (MPT | 16)
    int rows[9];
    #pragma unroll
    for (int s = 0; s < 9; ++s) rows[s] = idx[(v0 + vloc)*9 + s] * (16*CI);
    float dwv[72];
    #pragma unroll
    for (int j = 0; j < 8; ++j)
      #pragma unroll
      for (int s = 0; s < 9; ++s) dwv[j*9 + s] = dw[(size_t)(8*kg + j)*9 + s];

    #pragma unroll
    for (int i = 0; i < MPT; ++i) {
      const int m = mb + i;
      const unsigned short* base = pin + (size_t)(m & 15)*CI + 8*kg;
      float y[8];
      #pragma unroll
      for (int j = 0; j < 8; ++j) y[j] = 0.f;
      #pragma unroll
      for (int s = 0; s < 9; ++s) {
        const uint4 g = *(const uint4*)(base + rows[s]);
        y[0] += dwv[0*9+s]*lo16f(g.x); y[1] += dwv[1*9+s]*hi16f(g.x);
        y[2] += dwv[2*9+s]*lo16f(g.y); y[3] += dwv[3*9+s]*hi16f(g.y);
        y[4] += dwv[4*9+s]*lo16f(g.z); y[5] += dwv[5*9+s]*hi16f(g.z);
        y[6] += dwv[6*9+s]*lo16f(g.w); y[7] += dwv[7*9+s]*hi16f(g.w);
      }
      uint4 pkd;
      pkd.x = pk2h(y[0], y[1]); pkd.y = pk2h(y[2], y[3]);
      pkd.z = pk2h(y[4], y[5]); pkd.w = pk2h(y[6], y[7]);
      *(uint4*)&a_l[m][8*kg] = pkd;
    }
  }
  __syncthreads();

  // ---- MFMA phase: D = Ah*Bh + Ah*Bl*2^-11 ----
  const int w = t >> 6, l = t & 15, q = (t >> 4) & 3;
  f32x4 ah[4][NTW], ax[4][NTW];
  #pragma unroll
  for (int mt = 0; mt < 4; ++mt)
    #pragma unroll
    for (int n = 0; n < NTW; ++n)
      #pragma unroll
      for (int r = 0; r < 4; ++r) { ah[mt][n][r] = 0.f; ax[mt][n][r] = 0.f; }

  #pragma unroll
  for (int c = 0; c < CHUNKS; ++c) {
    const int k0 = c*32 + q*8;
    half8 fa[4], fbh[NTW], fbl[NTW];
    #pragma unroll
    for (int mt = 0; mt < 4; ++mt)
      fa[mt] = *(const half8*)&a_l[mt*16 + l][k0];
    #pragma unroll
    for (int n = 0; n < NTW; ++n) {
      const size_t boff = (size_t)((w*NTW + n)*16 + l)*CI + k0;
      fbh[n] = *(const half8*)(bhp + boff);
      fbl[n] = *(const half8*)(blp + boff);
    }
    #pragma unroll
    for (int mt = 0; mt < 4; ++mt)
      #pragma unroll
      for (int n = 0; n < NTW; ++n) {
        ah[mt][n] = __builtin_amdgcn_mfma_f32_16x16x32_f16(fa[mt], fbh[n], ah[mt][n], 0, 0, 0);
        ax[mt][n] = __builtin_amdgcn_mfma_f32_16x16x32_f16(fa[mt], fbl[n], ax[mt][n], 0, 0, 0);
      }
  }

  // ---- epilogue: D[row=q*4+r][col=lane&15], fp16 store ----
  #pragma unroll
  for (int mt = 0; mt < 4; ++mt)
    #pragma unroll
    for (int n = 0; n < NTW; ++n) {
      const int colg = (w*NTW + n)*16 + l;
      #pragma unroll
      for (int r = 0; r < 4; ++r) {
        const int row = mt*16 + q*4 + r;
        float v = ah[mt][n][r] + ax[mt][n][r] * (1.0f/2048.0f);
        if (RELU) v = fmaxf(v, 0.f);
        out[(size_t)(v0*16 + row)*CO + colg] = hbits(v);
      }
    }
}

// ---------------- head: spiral conv 64 -> 3 (fp32 math), output (b, v, 3) ----------------
__global__ __launch_bounds__(256) void k_head(
    const unsigned short* __restrict__ a, const int* __restrict__ idx,
    const float* __restrict__ dwh, const float* __restrict__ pwh,
    float* __restrict__ out, int nvert)
{
  const int wid  = blockIdx.x*4 + (threadIdx.x >> 6);
  const int lane = threadIdx.x & 63;
  const int v = wid >> 4, b = wid & 15;
  float y = 0.f;
  #pragma unroll
  for (int s = 0; s < 9; ++s) {
    int r = idx[v*9 + s];
    y += dwh[lane*9 + s] * h2f(a[((size_t)r*16 + b)*64 + lane]);
  }
  float p0 = y * pwh[lane*3+0];
  float p1 = y * pwh[lane*3+1];
  float p2 = y * pwh[lane*3+2];
  #pragma unroll
  for (int o = 32; o > 0; o >>= 1) {
    p0 += __shfl_xor(p0, o, 64);
    p1 += __shfl_xor(p1, o, 64);
    p2 += __shfl_xor(p2, o, 64);
  }
  if (lane == 0) {
    size_t off = ((size_t)b*nvert + v)*3;
    out[off+0] = p0; out[off+1] = p1; out[off+2] = p2;
  }
}

extern "C" void kernel_launch(void* const* d_in, const int* in_sizes, int n_in,
                              void* d_out, int out_size, void* d_ws, size_t ws_size,
                              hipStream_t stream)
{
  const float* uv   = (const float*)d_in[0];
  const float* feat = (const float*)d_in[1];
  const float* up   = (const float*)d_in[2];
  const float* dw0  = (const float*)d_in[3];
  const float* pw0  = (const float*)d_in[4];
  const float* dw1  = (const float*)d_in[5];
  const float* pw1  = (const float*)d_in[6];
  const float* dw2  = (const float*)d_in[7];
  const float* pw2  = (const float*)d_in[8];
  const float* dw3  = (const float*)d_in[9];
  const float* pw3  = (const float*)d_in[10];
  const float* dwh  = (const float*)d_in[11];
  const float* pwh  = (const float*)d_in[12];
  const int*   sp0  = (const int*)d_in[13];
  const int*   col0 = (const int*)d_in[14];
  const float* val0 = (const float*)d_in[15];
  const int*   sp1  = (const int*)d_in[16];
  const int*   col1 = (const int*)d_in[17];
  const float* val1 = (const float*)d_in[18];
  const int*   sp2  = (const int*)d_in[19];
  const int*   col2 = (const int*)d_in[20];
  const float* val2 = (const float*)d_in[21];
  const int*   sp3  = (const int*)d_in[22];
  const int*   col3 = (const int*)d_in[23];
  const float* val3 = (const float*)d_in[24];

  unsigned short* bufA = (unsigned short*)d_ws;                      // 25,690,112 B
  unsigned short* bufB = (unsigned short*)((char*)d_ws + 25690112);  // 51,380,224 B
  float* outp = (float*)d_out;

  // split pw tables in d_out scratch (overwritten by k_head at the end)
  unsigned short* pwT = (unsigned short*)d_out;
  unsigned short* h0 = pwT;            unsigned short* L0 = pwT + 172032;
  unsigned short* h1 = pwT + 65536;    unsigned short* L1 = L0 + 65536;
  unsigned short* h2 = pwT + 131072;   unsigned short* L2 = L0 + 131072;
  unsigned short* h3 = pwT + 163840;   unsigned short* L3 = L0 + 163840;

  k_prep<<<672, 256, 0, stream>>>(pw0, pw1, pw2, pw3, pwT);
  k_sample_up<<<dim3(14,16,1), 256, 0, stream>>>(uv, feat, up, bufA);

  k_pool<<<1568, 256, 0, stream>>>(bufA, col3, val3, bufB, 16*256);
  k_conv<256,256,true><<<392, 256, 0, stream>>>(bufB, sp3, dw0, h0, L0, bufA);

  k_pool<<<3136, 256, 0, stream>>>(bufA, col2, val2, bufB, 16*256);
  k_conv<256,256,true><<<784, 256, 0, stream>>>(bufB, sp2, dw1, h1, L1, bufA);

  k_pool<<<6272, 256, 0, stream>>>(bufA, col1, val1, bufB, 16*256);
  k_conv<256,128,true><<<1568, 256, 0, stream>>>(bufB, sp1, dw2, h2, L2, bufA);

  k_pool<<<12544, 256, 0, stream>>>(bufA, col0, val0, bufB, 16*128);
  k_conv<128,64,true><<<3136, 256, 0, stream>>>(bufB, sp0, dw3, h3, L3, bufA);

  k_head<<<50176, 256, 0, stream>>>(bufA, sp0, dwh, pwh, outp, 12544);
}